// Round 8
// baseline (123.758 us; speedup 1.0000x reference)
//
#include <hip/hip_runtime.h>
#include <hip/hip_bf16.h>

#define B_ 2
#define S_ 2048
#define D_ 1024
#define N_ 16
#define H_ 64

typedef unsigned short u16;
typedef unsigned int u32;
typedef __bf16 bf16x8 __attribute__((ext_vector_type(8)));
typedef u16 u16x8 __attribute__((ext_vector_type(8)));
typedef u32 u32x2 __attribute__((ext_vector_type(2)));
typedef float f4v __attribute__((ext_vector_type(4)));

__device__ __forceinline__ u16 f2b(float f) {
    u32 u = __builtin_bit_cast(u32, f);
    u32 r = (u + 0x7FFFu + ((u >> 16) & 1u)) >> 16;
    return (u16)r;
}
__device__ __forceinline__ bf16x8 asbf(u16x8 v) { return __builtin_bit_cast(bf16x8, v); }
__device__ __forceinline__ u32 cvtpk(float a, float b) {
    u32 r;
    asm("v_cvt_pk_bf16_f32 %0, %1, %2" : "=v"(r) : "v"(a), "v"(b));
    return r;
}
// async global->LDS, 16B per lane; LDS dest is wave-uniform base + lane*16
__device__ __forceinline__ void gload16(const u16* g, u16* l) {
    __builtin_amdgcn_global_load_lds((const __attribute__((address_space(1))) void*)g,
                                     (__attribute__((address_space(3))) void*)l, 16, 0, 0);
}

// ---------------------------------------------------------------------------
// convert x fp32 -> bf16 [4096][1024]
__global__ __launch_bounds__(256) void k_cvt_x(const float* __restrict__ x,
                                               u16* __restrict__ xb) {
    size_t i = ((size_t)blockIdx.x * 256 + threadIdx.x) * 8;
    float4 f0 = *(const float4*)(x + i);
    float4 f1 = *(const float4*)(x + i + 4);
    u16x8 o;
    o[0] = f2b(f0.x); o[1] = f2b(f0.y); o[2] = f2b(f0.z); o[3] = f2b(f0.w);
    o[4] = f2b(f1.x); o[5] = f2b(f1.y); o[6] = f2b(f1.z); o[7] = f2b(f1.w);
    *(u16x8*)(xb + i) = o;
}

// ---------------------------------------------------------------------------
// W_qkv fp32 [n][1024 d][192 j] -> bf16 TRANSPOSED wt [n][192 j][1024 d].
// Q columns (j<64) scaled by 0.125*log2(e) (exp2-domain softmax).
__global__ __launch_bounds__(256) void k_cvt_w(const float* __restrict__ w,
                                               u16* __restrict__ wt) {
    __shared__ float T[64][65];
    const int d0 = blockIdx.x * 64, jt = blockIdx.y, n = blockIdx.z;
    const int j0 = jt * 64;
    const float sc = (jt == 0) ? 0.125f * 1.44269504089f : 1.0f;
    const int t = threadIdx.x;
#pragma unroll
    for (int rep = 0; rep < 4; ++rep) {
        int v = t + rep * 256;
        int row = v >> 4, c4 = v & 15;
        float4 f = *(const float4*)(w + ((size_t)(n * 1024 + d0 + row)) * 192 + j0 + c4 * 4);
        T[row][c4 * 4 + 0] = f.x * sc;
        T[row][c4 * 4 + 1] = f.y * sc;
        T[row][c4 * 4 + 2] = f.z * sc;
        T[row][c4 * 4 + 3] = f.w * sc;
    }
    __syncthreads();
#pragma unroll
    for (int rep = 0; rep < 2; ++rep) {
        int c = t + rep * 256;
        int j = c >> 3, db = c & 7;
        u16x8 o;
#pragma unroll
        for (int e = 0; e < 8; ++e) o[e] = f2b(T[db * 8 + e][j]);
        *(u16x8*)(wt + ((size_t)(n * 192 + j0 + j)) * 1024 + d0 + db * 8) = o;
    }
}

// ---------------------------------------------------------------------------
// wsum[d] = sum over 1024 rows of W_out
__global__ __launch_bounds__(256) void k_wsum(const float* __restrict__ Wout,
                                              float* __restrict__ wsum) {
    __shared__ float red[16][17];
    const int dd = threadIdx.x & 15, rr = threadIdx.x >> 4;
    const int d = blockIdx.x * 16 + dd;
    float s = 0.f;
    for (int r = rr * 64; r < rr * 64 + 64; ++r) s += Wout[(size_t)r * 1024 + d];
    red[rr][dd] = s;
    __syncthreads();
    if (rr == 0) {
        float t = 0.f;
#pragma unroll
        for (int k = 0; k < 16; ++k) t += red[k][dd];
        wsum[d] = t;
    }
}

// ---------------------------------------------------------------------------
// QKV GEMM, MFMA bf16. Tile 128(M) x 192(N) x 64(K-step). 8 waves as 2M x 4N.
// Staging via global_load_lds width 16 into LINEAR LDS (m97 pattern).
__global__ __launch_bounds__(512) void k_qkv(const u16* __restrict__ xb,
                                             const u16* __restrict__ wt,
                                             u16* __restrict__ qbuf,
                                             u16* __restrict__ kbuf,
                                             u16* __restrict__ vt) {
    __shared__ u16 As[128 * 64];   // [row][64k] linear
    __shared__ u16 Bst[192 * 64];  // [j][64k]  linear
    const int st = blockIdx.x, n = blockIdx.y;
    const int t = threadIdx.x;
    const int w = t >> 6, lane = t & 63, hi2 = lane >> 4, lo4 = lane & 15;
    const int wm = w >> 2, wn = w & 3;  // 2M x 4N wave grid

    // per-lane global sources (16B each), wave-uniform LDS dests
    const int l8 = lane >> 3, l7 = (lane & 7) * 8;
    const u16* AgL = xb + (size_t)(st * 128 + w * 16 + l8) * 1024 + l7;
    u16* AdL = As + w * 16 * 64;
    const u16* BgL = wt + (size_t)(n * 192 + w * 24 + l8) * 1024 + l7;
    u16* BdL = Bst + w * 24 * 64;

    f4v acc[4][3];
#pragma unroll
    for (int i = 0; i < 4; ++i)
#pragma unroll
        for (int j = 0; j < 3; ++j) acc[i][j] = (f4v){0.f, 0.f, 0.f, 0.f};

    for (int kk = 0; kk < 16; ++kk) {
        __syncthreads();  // previous tile's reads complete
        const int ko = kk * 64;
        gload16(AgL + ko, AdL);
        gload16(AgL + ko + (size_t)8 * 1024, AdL + 8 * 64);
        gload16(BgL + ko, BdL);
        gload16(BgL + ko + (size_t)8 * 1024, BdL + 8 * 64);
        gload16(BgL + ko + (size_t)16 * 1024, BdL + 16 * 64);
        __syncthreads();  // drains vmcnt -> LDS ready
        bf16x8 fa[4][2];
#pragma unroll
        for (int ms = 0; ms < 4; ++ms) {
            const u16* ar = As + (wm * 64 + ms * 16 + lo4) * 64;
            fa[ms][0] = asbf(*(const u16x8*)(ar + hi2 * 8));
            fa[ms][1] = asbf(*(const u16x8*)(ar + hi2 * 8 + 32));
        }
        __builtin_amdgcn_s_setprio(1);
#pragma unroll
        for (int fj = 0; fj < 3; ++fj) {
            const u16* br = Bst + (wn * 48 + fj * 16 + lo4) * 64;
            bf16x8 fb0 = asbf(*(const u16x8*)(br + hi2 * 8));
            bf16x8 fb1 = asbf(*(const u16x8*)(br + hi2 * 8 + 32));
#pragma unroll
            for (int ms = 0; ms < 4; ++ms) {
                acc[ms][fj] = __builtin_amdgcn_mfma_f32_16x16x32_bf16(fa[ms][0], fb0, acc[ms][fj], 0, 0, 0);
                acc[ms][fj] = __builtin_amdgcn_mfma_f32_16x16x32_bf16(fa[ms][1], fb1, acc[ms][fj], 0, 0, 0);
            }
        }
        __builtin_amdgcn_s_setprio(0);
    }

    // epilogue: LDS bounce per section for vectorized global stores
    const int b = st >> 4, s128 = (st & 15) * 128;
    u16* Cs = As;
#pragma unroll
    for (int sec = 0; sec < 3; ++sec) {
        __syncthreads();
#pragma unroll
        for (int fj = 0; fj < 3; ++fj) {
            const int base = wn * 48 + fj * 16;
            if ((base >> 6) == sec) {
                const int col = base - sec * 64 + lo4;
#pragma unroll
                for (int ms = 0; ms < 4; ++ms)
#pragma unroll
                    for (int r = 0; r < 4; ++r)
                        Cs[(wm * 64 + ms * 16 + hi2 * 4 + r) * 64 + col] = f2b(acc[ms][fj][r]);
            }
        }
        __syncthreads();
        if (sec == 2) {
            const int h = t & 63, sb = t >> 6;
            u16x8 o0, o1;
#pragma unroll
            for (int e = 0; e < 8; ++e) o0[e] = Cs[(sb * 16 + e) * 64 + h];
#pragma unroll
            for (int e = 0; e < 8; ++e) o1[e] = Cs[(sb * 16 + 8 + e) * 64 + h];
            u16* dst = vt + ((size_t)(b * 16 + n) * 64 + h) * 2048 + s128 + sb * 16;
            *(u16x8*)dst = o0;
            *(u16x8*)(dst + 8) = o1;
        } else {
            const int row = t >> 2, off = (t & 3) * 16;
            u16* dst = (sec == 0) ? qbuf : kbuf;
            dst += ((size_t)(b * 16 + n) * 2048 + s128 + row) * 64 + off;
            *(u16x8*)dst = *(const u16x8*)(Cs + row * 64 + off);
            *(u16x8*)(dst + 8) = *(const u16x8*)(Cs + row * 64 + off + 8);
        }
    }
}

// ---------------------------------------------------------------------------
// MFMA flash attention, swapped-operand, WIDE waves: 2-wave block, QBLK=64,
// each wave owns 32 q (2 B-frag sets) so every K/V fragment read feeds 2x
// the MFMAs. KVBLK=64, grid 1024 heavy-first, 2-barrier reg-prefetch staging
// (R6-proven), exp2 softmax + defer-max, P via wave-private swizzled LDS.
__global__ __launch_bounds__(128) void k_attn(const u16* __restrict__ qbuf,
                                              const u16* __restrict__ kbuf,
                                              const u16* __restrict__ vt,
                                              float* __restrict__ obuf) {
    __shared__ u16 SMEM[12288];  // Ks 8KB | Vs 8KB | Ps 2x4KB = 24KB
    u16* Ks = SMEM;
    u16* Vs = SMEM + 4096;
    u16* Ps = SMEM + 8192;
    const int id = blockIdx.x;
    const int bn = id & 31;
    const int qb = 31 - (id >> 5);  // heavy q-tiles dispatched first
    const int t = threadIdx.x;
    const int w = t >> 6, lane = t & 63, hi2 = lane >> 4, lo4 = lane & 15;

    // Q as B-operand fragments; wave w covers q = qb*64 + w*32 + g*16 + lo4
    bf16x8 bq[2][2];
#pragma unroll
    for (int g = 0; g < 2; ++g) {
        const u16* Qp = qbuf + ((size_t)bn * 2048 + qb * 64 + w * 32 + g * 16 + lo4) * 64;
        bq[g][0] = asbf(*(const u16x8*)(Qp + hi2 * 8));
        bq[g][1] = asbf(*(const u16x8*)(Qp + 32 + hi2 * 8));
    }

    // staging: 128 thr, each 64B of K (row srow) and 64B of V (row srow)
    const int srow = t >> 1, sh = t & 1;
    const u16* Kg = kbuf + (size_t)bn * 2048 * 64 + (size_t)srow * 64 + sh * 32;
    const u16* Vg = vt + (size_t)bn * 64 * 2048 + (size_t)srow * 2048 + sh * 32;
    const int ssw = (srow & 7) << 3;
    int soff[4];
#pragma unroll
    for (int c = 0; c < 4; ++c) soff[c] = (sh * 32 + c * 8) ^ ssw;
    u16* Kl = Ks + srow * 64;
    u16* Vl = Vs + srow * 64;

    f4v accO[4][2];
#pragma unroll
    for (int i = 0; i < 4; ++i)
#pragma unroll
        for (int g = 0; g < 2; ++g) accO[i][g] = (f4v){0.f, 0.f, 0.f, 0.f};
    float m[2] = {-3.0e38f, -3.0e38f}, l[2] = {0.f, 0.f};

    const int rsw = (lo4 & 7) << 3;
    const int nkb = qb + 1;

    // prefetch tile 0 into regs
    u16x8 kr[4], vr[4];
#pragma unroll
    for (int c = 0; c < 4; ++c) {
        kr[c] = *(const u16x8*)(Kg + c * 8);
        vr[c] = *(const u16x8*)(Vg + c * 8);
    }

    for (int kb = 0; kb < nkb; ++kb) {
        __syncthreads();  // previous tile fully consumed
#pragma unroll
        for (int c = 0; c < 4; ++c) {
            *(u16x8*)(Kl + soff[c]) = kr[c];
            *(u16x8*)(Vl + soff[c]) = vr[c];
        }
        if (kb + 1 < nkb) {
#pragma unroll
            for (int c = 0; c < 4; ++c) {
                kr[c] = *(const u16x8*)(Kg + (size_t)(kb + 1) * 4096 + c * 8);
                vr[c] = *(const u16x8*)(Vg + (kb + 1) * 64 + c * 8);
            }
        }
        __syncthreads();  // staged tile visible

        // S^T = K Q : per g, D[kv][q], kv = fi*16 + hi2*4 + r
        f4v s4[2][4];
#pragma unroll
        for (int g = 0; g < 2; ++g)
#pragma unroll
            for (int i = 0; i < 4; ++i) s4[g][i] = (f4v){0.f, 0.f, 0.f, 0.f};
        __builtin_amdgcn_s_setprio(1);
#pragma unroll
        for (int fi = 0; fi < 4; ++fi) {
            const u16* krow = Ks + (fi * 16 + lo4) * 64;
            bf16x8 ka0 = asbf(*(const u16x8*)(krow + ((hi2 * 8) ^ rsw)));
            bf16x8 ka1 = asbf(*(const u16x8*)(krow + ((hi2 * 8 + 32) ^ rsw)));
#pragma unroll
            for (int g = 0; g < 2; ++g) {
                s4[g][fi] = __builtin_amdgcn_mfma_f32_16x16x32_bf16(ka0, bq[g][0], s4[g][fi], 0, 0, 0);
                s4[g][fi] = __builtin_amdgcn_mfma_f32_16x16x32_bf16(ka1, bq[g][1], s4[g][fi], 0, 0, 0);
            }
        }
        __builtin_amdgcn_s_setprio(0);

        // causal mask (diagonal tile only)
        if (kb == qb) {
#pragma unroll
            for (int g = 0; g < 2; ++g) {
                const int qg = qb * 64 + w * 32 + g * 16 + lo4;
#pragma unroll
                for (int fi = 0; fi < 4; ++fi)
#pragma unroll
                    for (int r = 0; r < 4; ++r) {
                        int kvg = kb * 64 + fi * 16 + hi2 * 4 + r;
                        if (kvg > qg) s4[g][fi][r] = -3.0e38f;
                    }
            }
        }

        // per-g online softmax (16 local kv + 2 shfl across hi2 quadrants)
#pragma unroll
        for (int g = 0; g < 2; ++g) {
            float pm = s4[g][0][0];
#pragma unroll
            for (int fi = 0; fi < 4; ++fi)
#pragma unroll
                for (int r = 0; r < 4; ++r) pm = fmaxf(pm, s4[g][fi][r]);
            pm = fmaxf(pm, __shfl_xor(pm, 16));
            pm = fmaxf(pm, __shfl_xor(pm, 32));

            if (__any(pm > m[g] + 8.0f)) {  // defer-max rescale
                float mn = fmaxf(m[g], pm);
                float fs = __builtin_exp2f(m[g] - mn);
                m[g] = mn;
                l[g] *= fs;
#pragma unroll
                for (int fh = 0; fh < 4; ++fh)
#pragma unroll
                    for (int r = 0; r < 4; ++r) accO[fh][g][r] *= fs;
            }
            float ts = 0.f;
            u16* Pwg = Ps + w * 2048 + (g * 16 + lo4) * 64;
#pragma unroll
            for (int fi = 0; fi < 4; ++fi) {
#pragma unroll
                for (int r = 0; r < 4; ++r) {
                    float pv = __builtin_exp2f(s4[g][fi][r] - m[g]);
                    s4[g][fi][r] = pv;
                    ts += pv;
                }
                u32x2 pk;
                pk[0] = cvtpk(s4[g][fi][0], s4[g][fi][1]);
                pk[1] = cvtpk(s4[g][fi][2], s4[g][fi][3]);
                *(u32x2*)(Pwg + ((fi * 16 + hi2 * 4) ^ rsw)) = pk;
            }
            ts += __shfl_xor(ts, 16);
            ts += __shfl_xor(ts, 32);
            l[g] += ts;
        }

        // O^T += V^T P^T (V frags shared across both g)
        bf16x8 pb[2][2];
#pragma unroll
        for (int g = 0; g < 2; ++g) {
            const u16* Pwg = Ps + w * 2048 + (g * 16 + lo4) * 64;
            pb[g][0] = asbf(*(const u16x8*)(Pwg + ((hi2 * 8) ^ rsw)));
            pb[g][1] = asbf(*(const u16x8*)(Pwg + ((32 + hi2 * 8) ^ rsw)));
        }
        __builtin_amdgcn_s_setprio(1);
#pragma unroll
        for (int fh = 0; fh < 4; ++fh) {
            const u16* vrow = Vs + (fh * 16 + lo4) * 64;
            bf16x8 va0 = asbf(*(const u16x8*)(vrow + ((hi2 * 8) ^ rsw)));
            bf16x8 va1 = asbf(*(const u16x8*)(vrow + ((hi2 * 8 + 32) ^ rsw)));
#pragma unroll
            for (int g = 0; g < 2; ++g) {
                accO[fh][g] = __builtin_amdgcn_mfma_f32_16x16x32_bf16(va0, pb[g][0], accO[fh][g], 0, 0, 0);
                accO[fh][g] = __builtin_amdgcn_mfma_f32_16x16x32_bf16(va1, pb[g][1], accO[fh][g], 0, 0, 0);
            }
        }
        __builtin_amdgcn_s_setprio(0);
    }

    // normalize + store fp32 [s][h] via direct float4 stores
#pragma unroll
    for (int g = 0; g < 2; ++g) {
        float inv = 1.f / l[g];
        float* orow = obuf + ((size_t)bn * 2048 + qb * 64 + w * 32 + g * 16 + lo4) * 64;
#pragma unroll
        for (int fh = 0; fh < 4; ++fh) {
            f4v o;
#pragma unroll
            for (int r = 0; r < 4; ++r) o[r] = accO[fh][g][r] * inv;
            *(f4v*)(orow + fh * 16 + hi2 * 4) = o;
        }
    }
}

// ---------------------------------------------------------------------------
// K4: permute + scale. final[b,s2,64n+rr] = attn[b,n, 32rr+s2/64, s2%64] * wsum[64n+rr]
__global__ __launch_bounds__(256) void k_perm(const float* __restrict__ obuf,
                                              const float* __restrict__ wsum,
                                              float* __restrict__ out) {
    __shared__ float T[64][65];
    const int tt = blockIdx.x, n = blockIdx.y, b = blockIdx.z;
    const int tid = threadIdx.x;
    const float* src = obuf + ((size_t)(b * 16 + n) * S_) * H_;
#pragma unroll
    for (int rep = 0; rep < 4; ++rep) {
        int v = tid + rep * 256;
        int r = v >> 4, h4 = v & 15;
        float4 f = *(const float4*)(src + (size_t)(r * 32 + tt) * H_ + h4 * 4);
        T[r][h4 * 4 + 0] = f.x;
        T[r][h4 * 4 + 1] = f.y;
        T[r][h4 * 4 + 2] = f.z;
        T[r][h4 * 4 + 3] = f.w;
    }
    __syncthreads();
#pragma unroll
    for (int rep = 0; rep < 4; ++rep) {
        int v = tid + rep * 256;
        int h = v >> 4, r4 = v & 15;
        float4 w4 = *(const float4*)(wsum + n * 64 + r4 * 4);
        float4 o4 = make_float4(T[r4 * 4 + 0][h] * w4.x, T[r4 * 4 + 1][h] * w4.y,
                                T[r4 * 4 + 2][h] * w4.z, T[r4 * 4 + 3][h] * w4.w);
        *(float4*)(out + ((size_t)(b * S_ + tt * 64 + h) * D_) + n * 64 + r4 * 4) = o4;
    }
}

// ---------------------------------------------------------------------------
extern "C" void kernel_launch(void* const* d_in, const int* in_sizes, int n_in,
                              void* d_out, int out_size, void* d_ws, size_t ws_size,
                              hipStream_t stream) {
    const float* x = (const float*)d_in[0];
    const float* Wqkv = (const float*)d_in[1];
    const float* Wout = (const float*)d_in[2];
    float* out = (float*)d_out;

    char* p = (char*)d_ws;
    float* wsum = (float*)p; p += 4096;
    u16* xb = (u16*)p; p += (size_t)4096 * 1024 * 2;          // 8 MB
    u16* wt = (u16*)p; p += (size_t)16 * 192 * 1024 * 2;      // 6 MB
    u16* qb_ = (u16*)p; p += (size_t)32 * 2048 * 64 * 2;      // 8 MB
    u16* kb_ = (u16*)p; p += (size_t)32 * 2048 * 64 * 2;      // 8 MB
    u16* vt_ = (u16*)p; p += (size_t)32 * 2048 * 64 * 2;      // 8 MB
    float* ob_ = (float*)p;                                   // 16 MB

    k_cvt_x<<<2048, 256, 0, stream>>>(x, xb);
    k_cvt_w<<<dim3(16, 3, 16), 256, 0, stream>>>(Wqkv, wt);
    k_wsum<<<64, 256, 0, stream>>>(Wout, wsum);
    k_qkv<<<dim3(32, 16), 512, 0, stream>>>(xb, wt, qb_, kb_, vt_);
    k_attn<<<1024, 128, 0, stream>>>(qb_, kb_, vt_, ob_);
    k_perm<<<dim3(32, 16, 2), 256, 0, stream>>>(ob_, wsum, out);
}

// Round 9
// 99.517 us; speedup vs baseline: 1.2436x; 1.2436x over previous
//
#include <hip/hip_runtime.h>
#include <hip/hip_bf16.h>

#define B_ 2
#define S_ 2048
#define D_ 1024
#define N_ 16
#define H_ 64

typedef unsigned short u16;
typedef unsigned int u32;
typedef __bf16 bf16x8 __attribute__((ext_vector_type(8)));
typedef u16 u16x8 __attribute__((ext_vector_type(8)));
typedef u32 u32x2 __attribute__((ext_vector_type(2)));
typedef float f4v __attribute__((ext_vector_type(4)));

__device__ __forceinline__ u16 f2b(float f) {
    u32 u = __builtin_bit_cast(u32, f);
    u32 r = (u + 0x7FFFu + ((u >> 16) & 1u)) >> 16;
    return (u16)r;
}
__device__ __forceinline__ bf16x8 asbf(u16x8 v) { return __builtin_bit_cast(bf16x8, v); }
__device__ __forceinline__ u32 cvtpk(float a, float b) {
    u32 r;
    asm("v_cvt_pk_bf16_f32 %0, %1, %2" : "=v"(r) : "v"(a), "v"(b));
    return r;
}
// async global->LDS, 16B per lane; LDS dest is wave-uniform base + lane*16
__device__ __forceinline__ void gload16(const u16* g, u16* l) {
    __builtin_amdgcn_global_load_lds((const __attribute__((address_space(1))) void*)g,
                                     (__attribute__((address_space(3))) void*)l, 16, 0, 0);
}

// ---------------------------------------------------------------------------
// convert x fp32 -> bf16 [4096][1024]
__global__ __launch_bounds__(256) void k_cvt_x(const float* __restrict__ x,
                                               u16* __restrict__ xb) {
    size_t i = ((size_t)blockIdx.x * 256 + threadIdx.x) * 8;
    float4 f0 = *(const float4*)(x + i);
    float4 f1 = *(const float4*)(x + i + 4);
    u16x8 o;
    o[0] = f2b(f0.x); o[1] = f2b(f0.y); o[2] = f2b(f0.z); o[3] = f2b(f0.w);
    o[4] = f2b(f1.x); o[5] = f2b(f1.y); o[6] = f2b(f1.z); o[7] = f2b(f1.w);
    *(u16x8*)(xb + i) = o;
}

// ---------------------------------------------------------------------------
// W_qkv fp32 [n][1024 d][192 j] -> bf16 TRANSPOSED wt [n][192 j][1024 d].
// Q columns (j<64) scaled by 0.125*log2(e) (exp2-domain softmax).
__global__ __launch_bounds__(256) void k_cvt_w(const float* __restrict__ w,
                                               u16* __restrict__ wt) {
    __shared__ float T[64][65];
    const int d0 = blockIdx.x * 64, jt = blockIdx.y, n = blockIdx.z;
    const int j0 = jt * 64;
    const float sc = (jt == 0) ? 0.125f * 1.44269504089f : 1.0f;
    const int t = threadIdx.x;
#pragma unroll
    for (int rep = 0; rep < 4; ++rep) {
        int v = t + rep * 256;
        int row = v >> 4, c4 = v & 15;
        float4 f = *(const float4*)(w + ((size_t)(n * 1024 + d0 + row)) * 192 + j0 + c4 * 4);
        T[row][c4 * 4 + 0] = f.x * sc;
        T[row][c4 * 4 + 1] = f.y * sc;
        T[row][c4 * 4 + 2] = f.z * sc;
        T[row][c4 * 4 + 3] = f.w * sc;
    }
    __syncthreads();
#pragma unroll
    for (int rep = 0; rep < 2; ++rep) {
        int c = t + rep * 256;
        int j = c >> 3, db = c & 7;
        u16x8 o;
#pragma unroll
        for (int e = 0; e < 8; ++e) o[e] = f2b(T[db * 8 + e][j]);
        *(u16x8*)(wt + ((size_t)(n * 192 + j0 + j)) * 1024 + d0 + db * 8) = o;
    }
}

// ---------------------------------------------------------------------------
// wsum[d] = sum over 1024 rows of W_out
__global__ __launch_bounds__(256) void k_wsum(const float* __restrict__ Wout,
                                              float* __restrict__ wsum) {
    __shared__ float red[16][17];
    const int dd = threadIdx.x & 15, rr = threadIdx.x >> 4;
    const int d = blockIdx.x * 16 + dd;
    float s = 0.f;
    for (int r = rr * 64; r < rr * 64 + 64; ++r) s += Wout[(size_t)r * 1024 + d];
    red[rr][dd] = s;
    __syncthreads();
    if (rr == 0) {
        float t = 0.f;
#pragma unroll
        for (int k = 0; k < 16; ++k) t += red[k][dd];
        wsum[d] = t;
    }
}

// ---------------------------------------------------------------------------
// QKV GEMM, MFMA bf16. Tile 128(M) x 192(N) x 64(K-step). 8 waves as 2M x 4N.
// Staging via global_load_lds width 16 into LINEAR LDS (m97 pattern).
__global__ __launch_bounds__(512) void k_qkv(const u16* __restrict__ xb,
                                             const u16* __restrict__ wt,
                                             u16* __restrict__ qbuf,
                                             u16* __restrict__ kbuf,
                                             u16* __restrict__ vt) {
    __shared__ u16 As[128 * 64];   // [row][64k] linear
    __shared__ u16 Bst[192 * 64];  // [j][64k]  linear
    const int st = blockIdx.x, n = blockIdx.y;
    const int t = threadIdx.x;
    const int w = t >> 6, lane = t & 63, hi2 = lane >> 4, lo4 = lane & 15;
    const int wm = w >> 2, wn = w & 3;  // 2M x 4N wave grid

    // per-lane global sources (16B each), wave-uniform LDS dests
    const int l8 = lane >> 3, l7 = (lane & 7) * 8;
    const u16* AgL = xb + (size_t)(st * 128 + w * 16 + l8) * 1024 + l7;
    u16* AdL = As + w * 16 * 64;
    const u16* BgL = wt + (size_t)(n * 192 + w * 24 + l8) * 1024 + l7;
    u16* BdL = Bst + w * 24 * 64;

    f4v acc[4][3];
#pragma unroll
    for (int i = 0; i < 4; ++i)
#pragma unroll
        for (int j = 0; j < 3; ++j) acc[i][j] = (f4v){0.f, 0.f, 0.f, 0.f};

    for (int kk = 0; kk < 16; ++kk) {
        __syncthreads();  // previous tile's reads complete
        const int ko = kk * 64;
        gload16(AgL + ko, AdL);
        gload16(AgL + ko + (size_t)8 * 1024, AdL + 8 * 64);
        gload16(BgL + ko, BdL);
        gload16(BgL + ko + (size_t)8 * 1024, BdL + 8 * 64);
        gload16(BgL + ko + (size_t)16 * 1024, BdL + 16 * 64);
        __syncthreads();  // drains vmcnt -> LDS ready
        bf16x8 fa[4][2];
#pragma unroll
        for (int ms = 0; ms < 4; ++ms) {
            const u16* ar = As + (wm * 64 + ms * 16 + lo4) * 64;
            fa[ms][0] = asbf(*(const u16x8*)(ar + hi2 * 8));
            fa[ms][1] = asbf(*(const u16x8*)(ar + hi2 * 8 + 32));
        }
        __builtin_amdgcn_s_setprio(1);
#pragma unroll
        for (int fj = 0; fj < 3; ++fj) {
            const u16* br = Bst + (wn * 48 + fj * 16 + lo4) * 64;
            bf16x8 fb0 = asbf(*(const u16x8*)(br + hi2 * 8));
            bf16x8 fb1 = asbf(*(const u16x8*)(br + hi2 * 8 + 32));
#pragma unroll
            for (int ms = 0; ms < 4; ++ms) {
                acc[ms][fj] = __builtin_amdgcn_mfma_f32_16x16x32_bf16(fa[ms][0], fb0, acc[ms][fj], 0, 0, 0);
                acc[ms][fj] = __builtin_amdgcn_mfma_f32_16x16x32_bf16(fa[ms][1], fb1, acc[ms][fj], 0, 0, 0);
            }
        }
        __builtin_amdgcn_s_setprio(0);
    }

    // epilogue: LDS bounce per section for vectorized global stores
    const int b = st >> 4, s128 = (st & 15) * 128;
    u16* Cs = As;
#pragma unroll
    for (int sec = 0; sec < 3; ++sec) {
        __syncthreads();
#pragma unroll
        for (int fj = 0; fj < 3; ++fj) {
            const int base = wn * 48 + fj * 16;
            if ((base >> 6) == sec) {
                const int col = base - sec * 64 + lo4;
#pragma unroll
                for (int ms = 0; ms < 4; ++ms)
#pragma unroll
                    for (int r = 0; r < 4; ++r)
                        Cs[(wm * 64 + ms * 16 + hi2 * 4 + r) * 64 + col] = f2b(acc[ms][fj][r]);
            }
        }
        __syncthreads();
        if (sec == 2) {
            const int h = t & 63, sb = t >> 6;
            u16x8 o0, o1;
#pragma unroll
            for (int e = 0; e < 8; ++e) o0[e] = Cs[(sb * 16 + e) * 64 + h];
#pragma unroll
            for (int e = 0; e < 8; ++e) o1[e] = Cs[(sb * 16 + 8 + e) * 64 + h];
            u16* dst = vt + ((size_t)(b * 16 + n) * 64 + h) * 2048 + s128 + sb * 16;
            *(u16x8*)dst = o0;
            *(u16x8*)(dst + 8) = o1;
        } else {
            const int row = t >> 2, off = (t & 3) * 16;
            u16* dst = (sec == 0) ? qbuf : kbuf;
            dst += ((size_t)(b * 16 + n) * 2048 + s128 + row) * 64 + off;
            *(u16x8*)dst = *(const u16x8*)(Cs + row * 64 + off);
            *(u16x8*)(dst + 8) = *(const u16x8*)(Cs + row * 64 + off + 8);
        }
    }
}

// ---------------------------------------------------------------------------
// MFMA flash attention, swapped-operand, R4-proven geometry: QBLK=128
// (8 waves x 16 q-cols), KVBLK=64, grid 512 heavy/light-paired. exp2-domain
// softmax + defer-max + cvt_pk P. FUSED epilogue: permute + wsum scale,
// writing final output directly (k_perm eliminated).
__global__ __launch_bounds__(512) void k_attn(const u16* __restrict__ qbuf,
                                              const u16* __restrict__ kbuf,
                                              const u16* __restrict__ vt,
                                              const float* __restrict__ wsum,
                                              float* __restrict__ out) {
    __shared__ u16 SMEM[16384];  // 32KB: Ks(8KB) | Vs(8KB) | Ps(16KB); reused as f32[128][64]
    u16* Ks = SMEM;
    u16* Vs = SMEM + 4096;
    u16* Ps = SMEM + 8192;
    const int id = blockIdx.x;
    const int bn = id & 31;
    const int qx = id >> 5;
    const int qb = (qx < 8) ? (15 - 2 * qx) : (2 * (qx - 8));  // heavy/light pairing
    const int t = threadIdx.x;
    const int w = t >> 6, lane = t & 63, hi2 = lane >> 4, lo4 = lane & 15;

    // Q as B-operand fragments (col = q = lo4, k = h = hi2*8+e)
    const int q = qb * 128 + w * 16 + lo4;
    const u16* Qp = qbuf + ((size_t)bn * 2048 + q) * 64;
    bf16x8 bq0 = asbf(*(const u16x8*)(Qp + hi2 * 8));
    bf16x8 bq1 = asbf(*(const u16x8*)(Qp + 32 + hi2 * 8));

    // staging (16B per thread per tile for K and V)
    const int srow = t >> 3, so = t & 7;
    const u16* Kg = kbuf + (size_t)bn * 2048 * 64 + (size_t)srow * 64 + so * 8;
    const u16* Vg = vt + (size_t)bn * 64 * 2048 + (size_t)srow * 2048 + so * 8;
    u16* Kl = Ks + srow * 64 + ((so * 8) ^ ((srow & 7) << 3));
    u16* Vl = Vs + srow * 64 + ((so * 8) ^ ((srow & 7) << 3));

    f4v accO[4];
#pragma unroll
    for (int i = 0; i < 4; ++i) accO[i] = (f4v){0.f, 0.f, 0.f, 0.f};
    float m = -3.0e38f, l = 0.f;

    const int rsw = (lo4 & 7) << 3;
    u16* Pw = Ps + w * 1024 + lo4 * 64;  // this lane's q-row
    const int nkb = 2 * qb + 2;

    u16x8 kreg = *(const u16x8*)(Kg);
    u16x8 vreg = *(const u16x8*)(Vg);

    for (int kb = 0; kb < nkb; ++kb) {
        __syncthreads();  // previous tile fully consumed
        *(u16x8*)Kl = kreg;
        *(u16x8*)Vl = vreg;
        if (kb + 1 < nkb) {
            kreg = *(const u16x8*)(Kg + (size_t)(kb + 1) * 4096);
            vreg = *(const u16x8*)(Vg + (kb + 1) * 64);
        }
        __syncthreads();  // staged tile visible

        // S^T = K Q : D[kv][q], kv = fi*16 + hi2*4 + r
        f4v s4[4];
#pragma unroll
        for (int i = 0; i < 4; ++i) s4[i] = (f4v){0.f, 0.f, 0.f, 0.f};
        __builtin_amdgcn_s_setprio(1);
#pragma unroll
        for (int fi = 0; fi < 4; ++fi) {
            const u16* kr = Ks + (fi * 16 + lo4) * 64;
            bf16x8 ka0 = asbf(*(const u16x8*)(kr + ((hi2 * 8) ^ rsw)));
            bf16x8 ka1 = asbf(*(const u16x8*)(kr + ((hi2 * 8 + 32) ^ rsw)));
            s4[fi] = __builtin_amdgcn_mfma_f32_16x16x32_bf16(ka0, bq0, s4[fi], 0, 0, 0);
            s4[fi] = __builtin_amdgcn_mfma_f32_16x16x32_bf16(ka1, bq1, s4[fi], 0, 0, 0);
        }
        __builtin_amdgcn_s_setprio(0);

        // causal mask (diagonal-straddling tiles only)
        if (kb >= 2 * qb) {
#pragma unroll
            for (int fi = 0; fi < 4; ++fi)
#pragma unroll
                for (int r = 0; r < 4; ++r) {
                    int kvg = kb * 64 + fi * 16 + hi2 * 4 + r;
                    if (kvg > q) s4[fi][r] = -3.0e38f;
                }
        }

        // per-lane softmax over 16 local kv (+2 shfl across hi2 quadrants)
        float pm = s4[0][0];
#pragma unroll
        for (int fi = 0; fi < 4; ++fi)
#pragma unroll
            for (int r = 0; r < 4; ++r) pm = fmaxf(pm, s4[fi][r]);
        pm = fmaxf(pm, __shfl_xor(pm, 16));
        pm = fmaxf(pm, __shfl_xor(pm, 32));

        if (__any(pm > m + 8.0f)) {  // defer-max rescale
            float mn = fmaxf(m, pm);
            float fs = __builtin_exp2f(m - mn);
            m = mn;
            l *= fs;
#pragma unroll
            for (int fh = 0; fh < 4; ++fh)
#pragma unroll
                for (int r = 0; r < 4; ++r) accO[fh][r] *= fs;
        }
        float ts = 0.f;
#pragma unroll
        for (int fi = 0; fi < 4; ++fi) {
#pragma unroll
            for (int r = 0; r < 4; ++r) {
                float pv = __builtin_exp2f(s4[fi][r] - m);
                s4[fi][r] = pv;
                ts += pv;
            }
            u32x2 pk;
            pk[0] = cvtpk(s4[fi][0], s4[fi][1]);
            pk[1] = cvtpk(s4[fi][2], s4[fi][3]);
            *(u32x2*)(Pw + ((fi * 16 + hi2 * 4) ^ rsw)) = pk;
        }
        ts += __shfl_xor(ts, 16);
        ts += __shfl_xor(ts, 32);
        l += ts;

        // O^T += V^T P^T
        bf16x8 pb0 = asbf(*(const u16x8*)(Pw + ((hi2 * 8) ^ rsw)));
        bf16x8 pb1 = asbf(*(const u16x8*)(Pw + ((32 + hi2 * 8) ^ rsw)));
        __builtin_amdgcn_s_setprio(1);
#pragma unroll
        for (int fh = 0; fh < 4; ++fh) {
            const u16* vr = Vs + (fh * 16 + lo4) * 64;
            bf16x8 va0 = asbf(*(const u16x8*)(vr + ((hi2 * 8) ^ rsw)));
            bf16x8 va1 = asbf(*(const u16x8*)(vr + ((hi2 * 8 + 32) ^ rsw)));
            accO[fh] = __builtin_amdgcn_mfma_f32_16x16x32_bf16(va0, pb0, accO[fh], 0, 0, 0);
            accO[fh] = __builtin_amdgcn_mfma_f32_16x16x32_bf16(va1, pb1, accO[fh], 0, 0, 0);
        }
        __builtin_amdgcn_s_setprio(0);
    }

    // ---- fused epilogue: permute + wsum scale, direct to final output ----
    // final[b, 64*(q%32)+h, 64n + q/32] = O[q,h] * wsum[64n + q/32]
    __syncthreads();
    float* Osh = (float*)SMEM;  // [128 ql][64 h], XOR-swizzled cols
    {
        float inv = 1.f / l;
        const int orl = w * 16 + lo4;     // ql = q % 128
        const int osw = (lo4 & 7) << 2;   // 4-f32 granule xor (key = ql&7)
        float* Or = Osh + orl * 64;
#pragma unroll
        for (int fh = 0; fh < 4; ++fh) {
            f4v o;
#pragma unroll
            for (int r = 0; r < 4; ++r) o[r] = accO[fh][r] * inv;
            *(f4v*)(Or + ((fh * 16 + hi2 * 4) ^ osw)) = o;
        }
    }
    __syncthreads();
    {
        const int b = bn >> 4, n = bn & 15;
        const int d0 = n * 64 + qb * 4;   // 4 contiguous output columns
        float4 wv = *(const float4*)(wsum + d0);
#pragma unroll
        for (int rep = 0; rep < 4; ++rep) {
            int p = rep * 512 + t;        // s2 = 64*tt + h, p in [0,2048)
            int h = p & 63, tt = p >> 6;  // tt = q%32
            const int key = (tt & 7) << 2;
            const int hc = h ^ key;
            float4 o;
            o.x = Osh[(tt)*64 + hc] * wv.x;        // ql = 0*32+tt
            o.y = Osh[(32 + tt) * 64 + hc] * wv.y; // ql = 1*32+tt
            o.z = Osh[(64 + tt) * 64 + hc] * wv.z; // ql = 2*32+tt
            o.w = Osh[(96 + tt) * 64 + hc] * wv.w; // ql = 3*32+tt
            *(float4*)(out + ((size_t)b * 2048 + p) * 1024 + d0) = o;
        }
    }
}

// ---------------------------------------------------------------------------
extern "C" void kernel_launch(void* const* d_in, const int* in_sizes, int n_in,
                              void* d_out, int out_size, void* d_ws, size_t ws_size,
                              hipStream_t stream) {
    const float* x = (const float*)d_in[0];
    const float* Wqkv = (const float*)d_in[1];
    const float* Wout = (const float*)d_in[2];
    float* out = (float*)d_out;

    char* p = (char*)d_ws;
    float* wsum = (float*)p; p += 4096;
    u16* xb = (u16*)p; p += (size_t)4096 * 1024 * 2;          // 8 MB
    u16* wt = (u16*)p; p += (size_t)16 * 192 * 1024 * 2;      // 6 MB
    u16* qb_ = (u16*)p; p += (size_t)32 * 2048 * 64 * 2;      // 8 MB
    u16* kb_ = (u16*)p; p += (size_t)32 * 2048 * 64 * 2;      // 8 MB
    u16* vt_ = (u16*)p; p += (size_t)32 * 2048 * 64 * 2;      // 8 MB

    k_cvt_x<<<2048, 256, 0, stream>>>(x, xb);
    k_cvt_w<<<dim3(16, 3, 16), 256, 0, stream>>>(Wqkv, wt);
    k_wsum<<<64, 256, 0, stream>>>(Wout, wsum);
    k_qkv<<<dim3(32, 16), 512, 0, stream>>>(xb, wt, qb_, kb_, vt_);
    k_attn<<<512, 512, 0, stream>>>(qb_, kb_, vt_, wsum, out);
}